// Round 16
// baseline (248.789 us; speedup 1.0000x reference)
//
#include <hip/hip_runtime.h>
#include <hip/hip_bf16.h>
#include <hip/hip_fp16.h>

// DeepSetPred R16 = R15 (free-running waves + frag-ordered A, 219us) with the
// token tile doubled 64->128. R15 post-mortem: L2 weight re-read = 2048 blocks
// x 1MB = 2GB at 41 B/cy/CU (~73% of L2 ceiling) -> L2-BW-bound. 128-token
// tile halves weight traffic to 1GB. NT=4/wave (acc 128 AGPR), 1 block/CU
// (137.7KB LDS), depth-2 A ring now has 512cy lead (8 MFMA/step) >> L2 lat.

typedef _Float16 half8v __attribute__((ext_vector_type(8)));
typedef _Float16 half4v __attribute__((ext_vector_type(4)));
typedef float f32x4 __attribute__((ext_vector_type(4)));
typedef float f32x16 __attribute__((ext_vector_type(16)));

#define TANH_SCALE 2.8853900817779268f  // 2*log2(e)
#define A_STR 1032                      // act row stride bytes (2-way-free, b64)
#define E_STRF 129                      // encT row stride (floats), 129%32=1

// ---------------- weight fragmentizer (unchanged from R15) ----------------
// Frag = [32 f][16 k] in MFMA A order: lane l holds f=ft*32+(l&31),
// k=ks*16+(l>>5)*8+j. Layer layout: frag index = ks*NFT + ft, 1KB each.
__global__ __launch_bounds__(256) void wt_kernel(
    const float* __restrict__ W1, const float* __restrict__ W2,
    const float* __restrict__ W3,
    _Float16* __restrict__ F1, _Float16* __restrict__ F2,
    _Float16* __restrict__ F3) {
    int u = blockIdx.x * 256 + threadIdx.x;       // 65536 lane-units
    const float* W; _Float16* F; int FW, NFT, u0; float scale;
    if (u < 16384)      { W = W1; F = F1; FW = 512; NFT = 16; u0 = u;         scale = TANH_SCALE; }
    else if (u < 49152) { W = W2; F = F2; FW = 512; NFT = 16; u0 = u - 16384; scale = TANH_SCALE; }
    else                { W = W3; F = F3; FW = 256; NFT = 8;  u0 = u - 49152; scale = 1.0f; }
    int lane = u0 & 63, frag = u0 >> 6;
    int ft = frag % NFT, ks = frag / NFT;
    int f = ft * 32 + (lane & 31);
    int k0 = ks * 16 + (lane >> 5) * 8;
    half8v v;
    #pragma unroll
    for (int j = 0; j < 8; ++j)
        v[j] = (_Float16)(W[(size_t)(k0 + j) * FW + f] * scale);
    *(half8v*)((char*)F + (size_t)u0 * 16) = v;
}

// B fragment from act LDS: two b64 reads (conflict-free at A_STR, measured)
__device__ __forceinline__ half8v read_b(const char* p, int off) {
    uint2 lo = *(const uint2*)(p + off);
    uint2 hi = *(const uint2*)(p + off + 8);
    uint4 w;
    w.x = lo.x; w.y = lo.y; w.z = hi.x; w.w = hi.y;
    return __builtin_bit_cast(half8v, w);
}

// ---------------- encoder pass: D[MT*32 f][NT*32 t] ----------------
// A from global (frag-ordered, depth-2 ring); B from LDS (depth-1 ring).
template<int K, int MT, int NT, int NFT>
__device__ __forceinline__ void mlp_pass32(const char* __restrict__ F, int wave,
                                           const char* lds_act,
                                           const float* sbias_layer, int lane,
                                           f32x16 acc[MT][NT]) {
    const int r2 = lane & 31;
    const int hi = lane >> 5;
    const int fbase = wave * (MT * 32);
    #pragma unroll
    for (int mt = 0; mt < MT; ++mt)
        #pragma unroll
        for (int q = 0; q < 4; ++q) {
            f32x4 bv = *(const f32x4*)(sbias_layer + fbase + mt * 32 + hi * 4 + q * 8);
            #pragma unroll
            for (int nt = 0; nt < NT; ++nt)
                #pragma unroll
                for (int j = 0; j < 4; ++j) acc[mt][nt][q * 4 + j] = bv[j];
        }
    const char* fb = F + ((size_t)wave * MT) * 1024 + lane * 16;
    const char* bb = lds_act + r2 * A_STR + hi * 16;

    constexpr int NS = K / 16;
    half8v A[3][MT], B[2][NT];
    #pragma unroll
    for (int mt = 0; mt < MT; ++mt) {
        A[0][mt] = *(const half8v*)(fb + mt * 1024);
        A[1][mt] = *(const half8v*)(fb + (NFT + mt) * 1024);
    }
    #pragma unroll
    for (int nt = 0; nt < NT; ++nt)
        B[0][nt] = read_b(bb, nt * 32 * A_STR);

    #pragma unroll
    for (int s = 0; s < NS; ++s) {
        if (s + 2 < NS) {
            #pragma unroll
            for (int mt = 0; mt < MT; ++mt)
                A[(s + 2) % 3][mt] =
                    *(const half8v*)(fb + ((size_t)(s + 2) * NFT + mt) * 1024);
        }
        if (s + 1 < NS) {
            #pragma unroll
            for (int nt = 0; nt < NT; ++nt)
                B[(s + 1) & 1][nt] = read_b(bb, nt * 32 * A_STR + (s + 1) * 32);
        }
        #pragma unroll
        for (int nt = 0; nt < NT; ++nt)
            #pragma unroll
            for (int mt = 0; mt < MT; ++mt)
                acc[mt][nt] = __builtin_amdgcn_mfma_f32_32x32x16_f16(
                    A[s % 3][mt], B[s & 1][nt], acc[mt][nt], 0, 0, 0);
    }
}

// acc (bias folded, pre-scaled) -> tanh -> fp16 LDS [t][f]
template<int MT, int NT>
__device__ __forceinline__ void store_h32(char* lds_out, const f32x16 acc[MT][NT],
                                          int fbase, int lane) {
    const int t_lo = lane & 31;
    const int hi = lane >> 5;
    #pragma unroll
    for (int mt = 0; mt < MT; ++mt)
        #pragma unroll
        for (int nt = 0; nt < NT; ++nt) {
            int t = nt * 32 + t_lo;
            #pragma unroll
            for (int q = 0; q < 4; ++q) {
                int f0 = fbase + mt * 32 + hi * 4 + q * 8;
                half4v hv;
                #pragma unroll
                for (int j = 0; j < 4; ++j) {
                    float e = __builtin_amdgcn_exp2f(acc[mt][nt][q * 4 + j]);
                    float rr = __builtin_amdgcn_rcpf(e + 1.0f);
                    hv[j] = (_Float16)fmaf(-2.0f, rr, 1.0f);
                }
                *(half4v*)(lds_out + t * A_STR + f0 * 2) = hv;
            }
        }
}

__global__ __launch_bounds__(512, 2) void encoder_kernel(
    const float* __restrict__ words, const int* __restrict__ seg_ids,
    const _Float16* __restrict__ F1, const _Float16* __restrict__ F2,
    const _Float16* __restrict__ F3,
    const float* __restrict__ b1, const float* __restrict__ b2,
    const float* __restrict__ b3, float* __restrict__ enc) {
    __shared__ __align__(16) char buf[132096];  // act 128x1032 / encT 256x129x4
    __shared__ __align__(16) float sbias[1280]; // s*b1(512) s*b2(512) b3(256)
    __shared__ int sseg[128];

    const int tid = threadIdx.x;
    const int lane = tid & 63;
    const int wave = tid >> 6;
    const int tok0 = blockIdx.x * 128;

    sbias[tid] = b1[tid] * TANH_SCALE;
    sbias[512 + tid] = b2[tid] * TANH_SCALE;
    if (tid < 256) sbias[1024 + tid] = b3[tid];
    if (tid < 128) sseg[tid] = seg_ids[tok0 + tid];

    // stage words tile -> fp16 LDS [t][k], 128 rows
    const float* wsrc = words + (size_t)tok0 * 256;
    #pragma unroll
    for (int it = 0; it < 16; ++it) {
        int i = it * 512 + tid;            // float4 index, 8192 total
        float4 v = ((const float4*)wsrc)[i];
        int t = i >> 6;
        int col = i & 63;
        half4v hv = { (_Float16)v.x, (_Float16)v.y, (_Float16)v.z, (_Float16)v.w };
        *(half4v*)(buf + t * A_STR + col * 8) = hv;
    }
    __syncthreads();

    // layer 1: words[128][256] -> h1[128][512] (in place)
    {
        f32x16 acc[2][4];
        mlp_pass32<256, 2, 4, 16>((const char*)F1, wave, buf, sbias, lane, acc);
        __syncthreads();
        store_h32<2, 4>(buf, acc, wave * 64, lane);
    }
    __syncthreads();

    // layer 2: h1 -> h2 (in place)
    {
        f32x16 acc[2][4];
        mlp_pass32<512, 2, 4, 16>((const char*)F2, wave, buf, sbias + 512, lane, acc);
        __syncthreads();
        store_h32<2, 4>(buf, acc, wave * 64, lane);
    }
    __syncthreads();

    // layer 3: h2 -> encT [256][129] f32 (in place; bias folded, no tanh)
    {
        f32x16 acc[1][4];
        mlp_pass32<512, 1, 4, 8>((const char*)F3, wave, buf, sbias + 1024, lane, acc);
        __syncthreads();
        float* encT = (float*)buf;
        const int t_lo = lane & 31;
        const int hi = lane >> 5;
        #pragma unroll
        for (int nt = 0; nt < 4; ++nt) {
            int t = nt * 32 + t_lo;
            #pragma unroll
            for (int q = 0; q < 4; ++q) {
                int f0 = wave * 32 + hi * 4 + q * 8;
                #pragma unroll
                for (int j = 0; j < 4; ++j)
                    encT[(f0 + j) * E_STRF + t] = acc[0][nt][q * 4 + j];
            }
        }
    }
    __syncthreads();

    // segment reduction: sorted seg_ids -> running sum, atomic on boundary
    {
        int f = tid & 255;
        int hh = tid >> 8;
        int t0 = hh * 64;
        const float* encT = (const float*)buf;
        float a = 0.0f;
        int cur = sseg[t0];
        for (int i = 0; i < 64; ++i) {
            int t = t0 + i;
            float v = encT[f * E_STRF + t];
            int s = sseg[t];
            if (s != cur) { atomicAdd(&enc[cur * 256 + f], a); a = 0.0f; cur = s; }
            a += v;
        }
        atomicAdd(&enc[cur * 256 + f], a);
    }
}

// ---------------- predictor (tiny, fp32) ----------------
__global__ __launch_bounds__(256) void pred_kernel(
    const float* __restrict__ enc,
    const float* __restrict__ P1, const float* __restrict__ pb1,
    const float* __restrict__ P2, const float* __restrict__ pb2,
    const float* __restrict__ P3, const float* __restrict__ pb3,
    float* __restrict__ out) {
    __shared__ float se[256];
    __shared__ float sp[512];
    __shared__ float red[256];
    const int tid = threadIdx.x, b = blockIdx.x;
    se[tid] = enc[b * 256 + tid];
    __syncthreads();
    float a0 = pb1[tid], a1 = pb1[tid + 256];
    for (int k = 0; k < 256; ++k) {
        float e = se[k];
        a0 = fmaf(e, P1[k * 512 + tid], a0);
        a1 = fmaf(e, P1[k * 512 + tid + 256], a1);
    }
    sp[tid] = tanhf(a0);
    sp[tid + 256] = tanhf(a1);
    __syncthreads();
    a0 = pb2[tid]; a1 = pb2[tid + 256];
    for (int k = 0; k < 512; ++k) {
        float p = sp[k];
        a0 = fmaf(p, P2[k * 512 + tid], a0);
        a1 = fmaf(p, P2[k * 512 + tid + 256], a1);
    }
    __syncthreads();
    sp[tid] = tanhf(a0);
    sp[tid + 256] = tanhf(a1);
    __syncthreads();
    int j = tid & 31, part = tid >> 5;
    float s = 0.0f;
    for (int k = part * 64; k < part * 64 + 64; ++k)
        s = fmaf(sp[k], P3[k * 32 + j], s);
    red[tid] = s;
    __syncthreads();
    if (tid < 128) red[tid] += red[tid + 128];
    __syncthreads();
    if (tid < 64) red[tid] += red[tid + 64];
    __syncthreads();
    if (tid < 32) out[b * 32 + tid] = red[tid] + red[tid + 32] + pb3[tid];
}

extern "C" void kernel_launch(void* const* d_in, const int* in_sizes, int n_in,
                              void* d_out, int out_size, void* d_ws, size_t ws_size,
                              hipStream_t stream) {
    const float* words = (const float*)d_in[0];
    const int* seg_ids = (const int*)d_in[1];
    const float* W1 = (const float*)d_in[2];
    const float* b1 = (const float*)d_in[3];
    const float* W2 = (const float*)d_in[4];
    const float* b2 = (const float*)d_in[5];
    const float* W3 = (const float*)d_in[6];
    const float* b3 = (const float*)d_in[7];
    const float* P1 = (const float*)d_in[8];
    const float* pb1 = (const float*)d_in[9];
    const float* P2 = (const float*)d_in[10];
    const float* pb2 = (const float*)d_in[11];
    const float* P3 = (const float*)d_in[12];
    const float* pb3 = (const float*)d_in[13];
    float* out = (float*)d_out;

    char* ws = (char*)d_ws;
    _Float16* F1 = (_Float16*)(ws);             // 256 frags = 262144 B
    _Float16* F2 = (_Float16*)(ws + 262144);    // 512 frags = 524288 B
    _Float16* F3 = (_Float16*)(ws + 786432);    // 256 frags = 262144 B
    float* enc = (float*)(ws + 1048576);        // 128*256*4 = 131072 B

    hipMemsetAsync(enc, 0, 128 * 256 * 4, stream);
    wt_kernel<<<256, 256, 0, stream>>>(W1, W2, W3, F1, F2, F3);
    encoder_kernel<<<1024, 512, 0, stream>>>(words, seg_ids, F1, F2, F3,
                                             b1, b2, b3, enc);
    pred_kernel<<<128, 256, 0, stream>>>(enc, P1, pb1, P2, pb2, P3, pb3, out);
}

// Round 17
// 235.795 us; speedup vs baseline: 1.0551x; 1.0551x over previous
//
#include <hip/hip_runtime.h>
#include <hip/hip_bf16.h>
#include <hip/hip_fp16.h>

// DeepSetPred R17 = R16's 128-token tile with TLP restored: 1024-thread block
// (16 waves = 4/SIMD, same as R15's winning TLP) instead of 512. R16 lost to
// 2 waves/SIMD exposure of every stall; R15 lost to 2x weight L2 traffic.
// R17 has both: 1GB weight traffic AND 4 waves/SIMD.
// Per-wave MT=1/NT=4 (acc 64 AGPR), 16 waves x 32 distinct features -> W read
// once per block. L3: 8 f-waves x 2 t-halves (NT=2). Free-running waves,
// frag-ordered A from L2 (depth-2 ring), B from LDS (depth-1 ring), 0-conflict
// 1032B act rows. Pipes/CU: MFMA 54us, A-L2 37us, LDS-B 53us -> overlap.

typedef _Float16 half8v __attribute__((ext_vector_type(8)));
typedef _Float16 half4v __attribute__((ext_vector_type(4)));
typedef float f32x4 __attribute__((ext_vector_type(4)));
typedef float f32x16 __attribute__((ext_vector_type(16)));

#define TANH_SCALE 2.8853900817779268f  // 2*log2(e)
#define A_STR 1032                      // act row stride bytes (2-way-free, b64)
#define E_STRF 129                      // encT row stride (floats)

// ---------------- weight fragmentizer (unchanged from R15) ----------------
// Frag = [32 f][16 k] in MFMA A order: lane l holds f=ft*32+(l&31),
// k=ks*16+(l>>5)*8+j. Layer layout: frag index = ks*NFT + ft, 1KB each.
__global__ __launch_bounds__(256) void wt_kernel(
    const float* __restrict__ W1, const float* __restrict__ W2,
    const float* __restrict__ W3,
    _Float16* __restrict__ F1, _Float16* __restrict__ F2,
    _Float16* __restrict__ F3) {
    int u = blockIdx.x * 256 + threadIdx.x;       // 65536 lane-units
    const float* W; _Float16* F; int FW, NFT, u0; float scale;
    if (u < 16384)      { W = W1; F = F1; FW = 512; NFT = 16; u0 = u;         scale = TANH_SCALE; }
    else if (u < 49152) { W = W2; F = F2; FW = 512; NFT = 16; u0 = u - 16384; scale = TANH_SCALE; }
    else                { W = W3; F = F3; FW = 256; NFT = 8;  u0 = u - 49152; scale = 1.0f; }
    int lane = u0 & 63, frag = u0 >> 6;
    int ft = frag % NFT, ks = frag / NFT;
    int f = ft * 32 + (lane & 31);
    int k0 = ks * 16 + (lane >> 5) * 8;
    half8v v;
    #pragma unroll
    for (int j = 0; j < 8; ++j)
        v[j] = (_Float16)(W[(size_t)(k0 + j) * FW + f] * scale);
    *(half8v*)((char*)F + (size_t)u0 * 16) = v;
}

// B fragment from act LDS: two b64 reads (conflict-free at A_STR, measured)
__device__ __forceinline__ half8v read_b(const char* p, int off) {
    uint2 lo = *(const uint2*)(p + off);
    uint2 hi = *(const uint2*)(p + off + 8);
    uint4 w;
    w.x = lo.x; w.y = lo.y; w.z = hi.x; w.w = hi.y;
    return __builtin_bit_cast(half8v, w);
}

// ---------------- encoder pass: D[32 f][NT*32 t], MT=1 ----------------
// A from global (frag-ordered, depth-2 ring); B from LDS (depth-1 ring).
// fragsel: which ft-frag this wave owns; tokofs: token offset (L3 t-halves).
template<int K, int NT, int NFT>
__device__ __forceinline__ void mlp_pass32(const char* __restrict__ F,
                                           int fragsel, int tokofs,
                                           const char* lds_act,
                                           const float* sbias_f, int lane,
                                           f32x16 acc[NT]) {
    const int r2 = lane & 31;
    const int hi = lane >> 5;
    #pragma unroll
    for (int q = 0; q < 4; ++q) {
        f32x4 bv = *(const f32x4*)(sbias_f + hi * 4 + q * 8);
        #pragma unroll
        for (int nt = 0; nt < NT; ++nt)
            #pragma unroll
            for (int j = 0; j < 4; ++j) acc[nt][q * 4 + j] = bv[j];
    }
    const char* fb = F + (size_t)fragsel * 1024 + lane * 16;
    const char* bb = lds_act + (size_t)(tokofs + r2) * A_STR + hi * 16;

    constexpr int NS = K / 16;
    half8v A[3], B[2][NT];
    A[0] = *(const half8v*)(fb);
    A[1] = *(const half8v*)(fb + (size_t)NFT * 1024);
    #pragma unroll
    for (int nt = 0; nt < NT; ++nt)
        B[0][nt] = read_b(bb, nt * 32 * A_STR);

    #pragma unroll
    for (int s = 0; s < NS; ++s) {
        if (s + 2 < NS)
            A[(s + 2) % 3] = *(const half8v*)(fb + ((size_t)(s + 2) * NFT) * 1024);
        if (s + 1 < NS) {
            #pragma unroll
            for (int nt = 0; nt < NT; ++nt)
                B[(s + 1) & 1][nt] = read_b(bb, nt * 32 * A_STR + (s + 1) * 32);
        }
        #pragma unroll
        for (int nt = 0; nt < NT; ++nt)
            acc[nt] = __builtin_amdgcn_mfma_f32_32x32x16_f16(
                A[s % 3], B[s & 1][nt], acc[nt], 0, 0, 0);
    }
}

// acc (bias folded, pre-scaled) -> tanh -> fp16 LDS [t][f]
template<int NT>
__device__ __forceinline__ void store_h32(char* lds_out, const f32x16 acc[NT],
                                          int fbase, int lane) {
    const int t_lo = lane & 31;
    const int hi = lane >> 5;
    #pragma unroll
    for (int nt = 0; nt < NT; ++nt) {
        int t = nt * 32 + t_lo;
        #pragma unroll
        for (int q = 0; q < 4; ++q) {
            int f0 = fbase + hi * 4 + q * 8;
            half4v hv;
            #pragma unroll
            for (int j = 0; j < 4; ++j) {
                float e = __builtin_amdgcn_exp2f(acc[nt][q * 4 + j]);
                float rr = __builtin_amdgcn_rcpf(e + 1.0f);
                hv[j] = (_Float16)fmaf(-2.0f, rr, 1.0f);
            }
            *(half4v*)(lds_out + t * A_STR + f0 * 2) = hv;
        }
    }
}

__global__ __launch_bounds__(1024, 1) void encoder_kernel(
    const float* __restrict__ words, const int* __restrict__ seg_ids,
    const _Float16* __restrict__ F1, const _Float16* __restrict__ F2,
    const _Float16* __restrict__ F3,
    const float* __restrict__ b1, const float* __restrict__ b2,
    const float* __restrict__ b3, float* __restrict__ enc) {
    __shared__ __align__(16) char buf[132096];  // act 128x1032 / encT 256x129x4
    __shared__ __align__(16) float sbias[1280]; // s*b1(512) s*b2(512) b3(256)
    __shared__ int sseg[128];

    const int tid = threadIdx.x;
    const int lane = tid & 63;
    const int wave = tid >> 6;                  // 0..15
    const int tok0 = blockIdx.x * 128;

    if (tid < 512) sbias[tid] = b1[tid] * TANH_SCALE;
    else           sbias[tid] = b2[tid - 512] * TANH_SCALE;
    if (tid < 256) sbias[1024 + tid] = b3[tid];
    if (tid < 128) sseg[tid] = seg_ids[tok0 + tid];

    // stage words tile -> fp16 LDS [t][k], 128 rows
    const float* wsrc = words + (size_t)tok0 * 256;
    #pragma unroll
    for (int it = 0; it < 8; ++it) {
        int i = it * 1024 + tid;           // float4 index, 8192 total
        float4 v = ((const float4*)wsrc)[i];
        int t = i >> 6;
        int col = i & 63;
        half4v hv = { (_Float16)v.x, (_Float16)v.y, (_Float16)v.z, (_Float16)v.w };
        *(half4v*)(buf + t * A_STR + col * 8) = hv;
    }
    __syncthreads();

    // layer 1: words[128][256] -> h1[128][512] (in place); wave owns 32 f
    {
        f32x16 acc[4];
        mlp_pass32<256, 4, 16>((const char*)F1, wave, 0, buf,
                               sbias + wave * 32, lane, acc);
        __syncthreads();
        store_h32<4>(buf, acc, wave * 32, lane);
    }
    __syncthreads();

    // layer 2: h1 -> h2 (in place)
    {
        f32x16 acc[4];
        mlp_pass32<512, 4, 16>((const char*)F2, wave, 0, buf,
                               sbias + 512 + wave * 32, lane, acc);
        __syncthreads();
        store_h32<4>(buf, acc, wave * 32, lane);
    }
    __syncthreads();

    // layer 3: h2 -> encT [256][129] f32; 8 f-waves x 2 t-halves
    {
        const int fw = wave >> 1, tw = wave & 1;
        f32x16 acc[2];
        mlp_pass32<512, 2, 8>((const char*)F3, fw, tw * 64, buf,
                              sbias + 1024 + fw * 32, lane, acc);
        __syncthreads();
        float* encT = (float*)buf;
        const int t_lo = lane & 31;
        const int hi = lane >> 5;
        #pragma unroll
        for (int nt = 0; nt < 2; ++nt) {
            int t = tw * 64 + nt * 32 + t_lo;
            #pragma unroll
            for (int q = 0; q < 4; ++q) {
                int f0 = fw * 32 + hi * 4 + q * 8;
                #pragma unroll
                for (int j = 0; j < 4; ++j)
                    encT[(f0 + j) * E_STRF + t] = acc[nt][q * 4 + j];
            }
        }
    }
    __syncthreads();

    // segment reduction: sorted seg_ids -> running sum, atomic on boundary
    {
        int f = tid & 255;
        int qq = tid >> 8;                  // 4 quarters x 32 tokens
        int t0 = qq * 32;
        const float* encT = (const float*)buf;
        float a = 0.0f;
        int cur = sseg[t0];
        for (int i = 0; i < 32; ++i) {
            int t = t0 + i;
            float v = encT[f * E_STRF + t];
            int s = sseg[t];
            if (s != cur) { atomicAdd(&enc[cur * 256 + f], a); a = 0.0f; cur = s; }
            a += v;
        }
        atomicAdd(&enc[cur * 256 + f], a);
    }
}

// ---------------- predictor (tiny, fp32) ----------------
__global__ __launch_bounds__(256) void pred_kernel(
    const float* __restrict__ enc,
    const float* __restrict__ P1, const float* __restrict__ pb1,
    const float* __restrict__ P2, const float* __restrict__ pb2,
    const float* __restrict__ P3, const float* __restrict__ pb3,
    float* __restrict__ out) {
    __shared__ float se[256];
    __shared__ float sp[512];
    __shared__ float red[256];
    const int tid = threadIdx.x, b = blockIdx.x;
    se[tid] = enc[b * 256 + tid];
    __syncthreads();
    float a0 = pb1[tid], a1 = pb1[tid + 256];
    for (int k = 0; k < 256; ++k) {
        float e = se[k];
        a0 = fmaf(e, P1[k * 512 + tid], a0);
        a1 = fmaf(e, P1[k * 512 + tid + 256], a1);
    }
    sp[tid] = tanhf(a0);
    sp[tid + 256] = tanhf(a1);
    __syncthreads();
    a0 = pb2[tid]; a1 = pb2[tid + 256];
    for (int k = 0; k < 512; ++k) {
        float p = sp[k];
        a0 = fmaf(p, P2[k * 512 + tid], a0);
        a1 = fmaf(p, P2[k * 512 + tid + 256], a1);
    }
    __syncthreads();
    sp[tid] = tanhf(a0);
    sp[tid + 256] = tanhf(a1);
    __syncthreads();
    int j = tid & 31, part = tid >> 5;
    float s = 0.0f;
    for (int k = part * 64; k < part * 64 + 64; ++k)
        s = fmaf(sp[k], P3[k * 32 + j], s);
    red[tid] = s;
    __syncthreads();
    if (tid < 128) red[tid] += red[tid + 128];
    __syncthreads();
    if (tid < 64) red[tid] += red[tid + 64];
    __syncthreads();
    if (tid < 32) out[b * 32 + tid] = red[tid] + red[tid + 32] + pb3[tid];
}

extern "C" void kernel_launch(void* const* d_in, const int* in_sizes, int n_in,
                              void* d_out, int out_size, void* d_ws, size_t ws_size,
                              hipStream_t stream) {
    const float* words = (const float*)d_in[0];
    const int* seg_ids = (const int*)d_in[1];
    const float* W1 = (const float*)d_in[2];
    const float* b1 = (const float*)d_in[3];
    const float* W2 = (const float*)d_in[4];
    const float* b2 = (const float*)d_in[5];
    const float* W3 = (const float*)d_in[6];
    const float* b3 = (const float*)d_in[7];
    const float* P1 = (const float*)d_in[8];
    const float* pb1 = (const float*)d_in[9];
    const float* P2 = (const float*)d_in[10];
    const float* pb2 = (const float*)d_in[11];
    const float* P3 = (const float*)d_in[12];
    const float* pb3 = (const float*)d_in[13];
    float* out = (float*)d_out;

    char* ws = (char*)d_ws;
    _Float16* F1 = (_Float16*)(ws);             // 256 frags = 262144 B
    _Float16* F2 = (_Float16*)(ws + 262144);    // 512 frags = 524288 B
    _Float16* F3 = (_Float16*)(ws + 786432);    // 256 frags = 262144 B
    float* enc = (float*)(ws + 1048576);        // 128*256*4 = 131072 B

    hipMemsetAsync(enc, 0, 128 * 256 * 4, stream);
    wt_kernel<<<256, 256, 0, stream>>>(W1, W2, W3, F1, F2, F3);
    encoder_kernel<<<1024, 1024, 0, stream>>>(words, seg_ids, F1, F2, F3,
                                              b1, b2, b3, enc);
    pred_kernel<<<128, 256, 0, stream>>>(enc, P1, pb1, P2, pb2, P3, pb3, out);
}